// Round 6
// baseline (165.575 us; speedup 1.0000x reference)
//
#include <hip/hip_runtime.h>
#include <math.h>

#define W 960
#define NROWS (16 * 544)            // 8704 flat (b,h) rows
#define ROWS_PB 4
#define NBLOCKS (NROWS / ROWS_PB)   // 2176
#define TPB 320                     // 5 waves; 960 float4 / 320 = 3 uniform iters
#define ITERS 3
#define ELEMS_PB (ROWS_PB * W)      // 3840 floats per region
#define PBV4 (ELEMS_PB / 4)         // 960 float4 per block

__device__ __forceinline__ float smooth_l1f(float d) {
    float ad = fabsf(d);
    return ad < 1.0f ? 0.5f * d * d : ad - 0.5f;
}

// LDS regions: [0]=seg_r, [1]=dl, [2]=lgt, [3]=dlgt — each ELEMS_PB floats,
// unpadded (global_load_lds writes wave-uniform base + lane*16, no padding allowed).
__global__ __launch_bounds__(TPB) void loss_kernel(
    const float* __restrict__ dl,
    const float* __restrict__ seg_r,
    const float* __restrict__ dlgt,
    const float* __restrict__ lgt,
    double* __restrict__ ws)
{
    __shared__ float lds_all[4 * ELEMS_PB];   // 61,440 B -> 2 blocks/CU
    const int tid       = threadIdx.x;
    const int wave      = tid >> 6;
    const int lane      = tid & 63;
    const int blockBase = blockIdx.x * ELEMS_PB;

    // ---- async DMA: 4 regions x 15 chunks of 1KB; wave w takes chunks w, w+5, w+10
    // of each region. 12 wave-insts in flight per wave, no VGPR round-trip.
    #pragma unroll
    for (int r = 0; r < 4; ++r) {
        const float* src = (r == 0) ? seg_r : (r == 1) ? dl : (r == 2) ? lgt : dlgt;
        #pragma unroll
        for (int i = 0; i < 3; ++i) {
            int off = (wave + i * 5) * 256;              // floats, wave-uniform
            __builtin_amdgcn_global_load_lds(
                (const __attribute__((address_space(1))) void*)(src + blockBase + off + lane * 4),
                (__attribute__((address_space(3))) void*)&lds_all[r * ELEMS_PB + off],
                16, 0, 0);
        }
    }
    __syncthreads();   // single vmcnt(0) drain for all 12 DMAs

    // ---- all compute on-chip: b128 LDS reads + pair-gather + VALU ----
    float cnt = 0.f, s_loss = 0.f, s_recon = 0.f;
    #pragma unroll
    for (int j = 0; j < ITERS; ++j) {
        int t  = tid + j * TPB;          // float4 index in block, < 960
        int r  = t / 240;                // row (240 float4 per row)
        int c4 = t - r * 240;
        const float* __restrict__ lrow = &lds_all[r * W];           // seg region
        float4 d4 = *(const float4*)&lds_all[1 * ELEMS_PB + 4 * t];
        float4 l4 = *(const float4*)&lds_all[2 * ELEMS_PB + 4 * t];
        float4 t4 = *(const float4*)&lds_all[3 * ELEMS_PB + 4 * t];
        float dv[4] = {d4.x, d4.y, d4.z, d4.w};
        float lv[4] = {l4.x, l4.y, l4.z, l4.w};
        float tv[4] = {t4.x, t4.y, t4.z, t4.w};
        #pragma unroll
        for (int k = 0; k < 4; ++k) {
            float m = lv[k] > 0.f ? 1.f : 0.f;
            cnt += m;
            float d = dv[k];
            s_loss += m * smooth_l1f(d - tv[k]);

            float sx  = (float)((c4 << 2) + k) - d;
            float x0f = floorf(sx);
            float wx  = sx - x0f;
            int x0 = (int)x0f;
            int x1 = x0 + 1;
            float m0 = (x0 >= 0 && x0 < W) ? 1.f : 0.f;
            float m1 = (x1 >= 0 && x1 < W) ? 1.f : 0.f;
            // adjacent-pair gather: one ds_read2 instead of two independent reads
            int xb = min(max(x0, 0), W - 2);
            float p0 = lrow[xb];
            float p1 = lrow[xb + 1];
            bool  c  = (x0 == xb);
            float g0 = (c ? p0 : p1) * m0;   // x0=W-1 -> p1; x0<0 masked
            float g1 = (c ? p1 : p0) * m1;   // x0=-1 -> p0=row[0]
            float wv = fmaf(wx, g1 - g0, g0);
            float recon = 1.f / (1.f + __expf(-wv));
            s_recon += m * smooth_l1f(recon - lv[k]);
        }
    }

    // ---- block reduction: wave shuffle (double) then LDS across 5 waves ----
    double dc = (double)cnt, dlo = (double)s_loss, dre = (double)s_recon;
    for (int off = 32; off > 0; off >>= 1) {
        dc  += __shfl_down(dc,  off, 64);
        dlo += __shfl_down(dlo, off, 64);
        dre += __shfl_down(dre, off, 64);
    }
    __shared__ double sh[3][TPB / 64];
    if (lane == 0) { sh[0][wave] = dc; sh[1][wave] = dlo; sh[2][wave] = dre; }
    __syncthreads();

    if (tid == 0) {
        double c = 0, l = 0, r = 0;
        #pragma unroll
        for (int j = 0; j < TPB / 64; ++j) { c += sh[0][j]; l += sh[1][j]; r += sh[2][j]; }
        double* slot = ws + blockIdx.x * 4;   // plain stores, zero contention
        slot[0] = c; slot[1] = l; slot[2] = r;
    }
}

__global__ __launch_bounds__(256) void finalize_kernel(
    const double* __restrict__ ws, float* __restrict__ out)
{
    double c = 0, l = 0, r = 0;
    for (int i = threadIdx.x; i < NBLOCKS; i += 256) {
        const double* slot = ws + i * 4;
        c += slot[0]; l += slot[1]; r += slot[2];
    }
    for (int off = 32; off > 0; off >>= 1) {
        c += __shfl_down(c, off, 64);
        l += __shfl_down(l, off, 64);
        r += __shfl_down(r, off, 64);
    }
    __shared__ double sh[3][4];
    int lane = threadIdx.x & 63, wid = threadIdx.x >> 6;
    if (lane == 0) { sh[0][wid] = c; sh[1][wid] = l; sh[2][wid] = r; }
    __syncthreads();
    if (threadIdx.x == 0) {
        double cc = 0, ll = 0, rr = 0;
        #pragma unroll
        for (int j = 0; j < 4; ++j) { cc += sh[0][j]; ll += sh[1][j]; rr += sh[2][j]; }
        double loss = ll / cc;
        if (isnan(loss)) loss = 0.0;
        out[0] = (float)(loss + 0.5 * (rr / cc));
    }
}

extern "C" void kernel_launch(void* const* d_in, const int* in_sizes, int n_in,
                              void* d_out, int out_size, void* d_ws, size_t ws_size,
                              hipStream_t stream) {
    const float* dl    = (const float*)d_in[0];
    const float* seg_r = (const float*)d_in[1];
    const float* dlgt  = (const float*)d_in[2];
    const float* lgt   = (const float*)d_in[3];
    double* ws = (double*)d_ws;   // 4 * NBLOCKS doubles; every used slot written each call

    loss_kernel<<<NBLOCKS, TPB, 0, stream>>>(dl, seg_r, dlgt, lgt, ws);
    finalize_kernel<<<1, 256, 0, stream>>>(ws, (float*)d_out);
}

// Round 8
// 149.145 us; speedup vs baseline: 1.1102x; 1.1102x over previous
//
#include <hip/hip_runtime.h>
#include <math.h>

#define W 960
#define NTOT (16 * 544 * 960)
#define N4 (NTOT / 4)               // 2,088,960 float4
#define TPB 256
#define NBLOCKS 2048                // 8 blocks/CU * 256 CUs; 32 waves/CU

typedef float vfloat4 __attribute__((ext_vector_type(4)));  // native vec for builtins

__device__ __forceinline__ float smooth_l1f(float d) {
    float ad = fabsf(d);
    return ad < 1.0f ? 0.5f * d * d : ad - 0.5f;
}

// Streaming, barrier-free fused loss. ws: per-block slot of 4 doubles.
__global__ __launch_bounds__(TPB) void loss_kernel(
    const float* __restrict__ dl,
    const float* __restrict__ seg_r,
    const float* __restrict__ dlgt,
    const float* __restrict__ lgt,
    double* __restrict__ ws)
{
    const int tid = threadIdx.x;
    float cnt = 0.f, s_loss = 0.f, s_recon = 0.f;

    for (int i4 = blockIdx.x * TPB + tid; i4 < N4; i4 += NBLOCKS * TPB) {
        int i  = i4 << 2;
        int w0 = i % W;                       // W%4==0: all 4 elems in same row
        const float* __restrict__ row = seg_r + (i - w0);

        // streamed arrays: nontemporal (don't thrash L1; L1 reserved for gathers)
        vfloat4 d4 = __builtin_nontemporal_load((const vfloat4*)dl   + i4);
        vfloat4 l4 = __builtin_nontemporal_load((const vfloat4*)lgt  + i4);
        vfloat4 t4 = __builtin_nontemporal_load((const vfloat4*)dlgt + i4);

        #pragma unroll
        for (int k = 0; k < 4; ++k) {
            float lv = l4[k];
            float m = lv > 0.f ? 1.f : 0.f;
            cnt += m;
            float d = d4[k];
            s_loss += m * smooth_l1f(d - t4[k]);

            float sx  = (float)(w0 + k) - d;
            float x0f = floorf(sx);
            float wx  = sx - x0f;
            int x0 = (int)x0f;
            int x1 = x0 + 1;
            float m0 = (x0 >= 0 && x0 < W) ? 1.f : 0.f;
            float m1 = (x1 >= 0 && x1 < W) ? 1.f : 0.f;
            int x0c = min(max(x0, 0), W - 1);
            int x1c = min(max(x1, 0), W - 1);
            float g0 = row[x0c] * m0;          // cached gathers, hot L1 window
            float g1 = row[x1c] * m1;
            float wv = fmaf(wx, g1 - g0, g0);
            float recon = 1.f / (1.f + __expf(-wv));
            s_recon += m * smooth_l1f(recon - lv);
        }
    }

    // block reduction: wave shuffle (double) then LDS across 4 waves
    double dc = (double)cnt, dlo = (double)s_loss, dre = (double)s_recon;
    for (int off = 32; off > 0; off >>= 1) {
        dc  += __shfl_down(dc,  off, 64);
        dlo += __shfl_down(dlo, off, 64);
        dre += __shfl_down(dre, off, 64);
    }
    __shared__ double sh[3][TPB / 64];
    int lane = tid & 63, wid = tid >> 6;
    if (lane == 0) { sh[0][wid] = dc; sh[1][wid] = dlo; sh[2][wid] = dre; }
    __syncthreads();

    if (tid == 0) {
        double c = 0, l = 0, r = 0;
        #pragma unroll
        for (int j = 0; j < TPB / 64; ++j) { c += sh[0][j]; l += sh[1][j]; r += sh[2][j]; }
        double* slot = ws + blockIdx.x * 4;   // plain stores, zero contention
        slot[0] = c; slot[1] = l; slot[2] = r;
    }
}

__global__ __launch_bounds__(256) void finalize_kernel(
    const double* __restrict__ ws, float* __restrict__ out)
{
    double c = 0, l = 0, r = 0;
    for (int i = threadIdx.x; i < NBLOCKS; i += 256) {
        const double* slot = ws + i * 4;
        c += slot[0]; l += slot[1]; r += slot[2];
    }
    for (int off = 32; off > 0; off >>= 1) {
        c += __shfl_down(c, off, 64);
        l += __shfl_down(l, off, 64);
        r += __shfl_down(r, off, 64);
    }
    __shared__ double sh[3][4];
    int lane = threadIdx.x & 63, wid = threadIdx.x >> 6;
    if (lane == 0) { sh[0][wid] = c; sh[1][wid] = l; sh[2][wid] = r; }
    __syncthreads();
    if (threadIdx.x == 0) {
        double cc = 0, ll = 0, rr = 0;
        #pragma unroll
        for (int j = 0; j < 4; ++j) { cc += sh[0][j]; ll += sh[1][j]; rr += sh[2][j]; }
        double loss = ll / cc;
        if (isnan(loss)) loss = 0.0;
        out[0] = (float)(loss + 0.5 * (rr / cc));
    }
}

extern "C" void kernel_launch(void* const* d_in, const int* in_sizes, int n_in,
                              void* d_out, int out_size, void* d_ws, size_t ws_size,
                              hipStream_t stream) {
    const float* dl    = (const float*)d_in[0];
    const float* seg_r = (const float*)d_in[1];
    const float* dlgt  = (const float*)d_in[2];
    const float* lgt   = (const float*)d_in[3];
    double* ws = (double*)d_ws;   // 4 * NBLOCKS doubles; every slot written each call

    loss_kernel<<<NBLOCKS, TPB, 0, stream>>>(dl, seg_r, dlgt, lgt, ws);
    finalize_kernel<<<1, 256, 0, stream>>>(ws, (float*)d_out);
}

// Round 9
// 148.816 us; speedup vs baseline: 1.1126x; 1.0022x over previous
//
#include <hip/hip_runtime.h>
#include <math.h>

#define W 960
#define NTOT (16 * 544 * 960)
#define N4 (NTOT / 4)               // 2,088,960 float4
#define TPB 256
#define NBLOCKS 2040                // 2040*256*4 == N4 exactly -> uniform 4 iters
#define STRIDE (NBLOCKS * TPB)      // 522,240

typedef float vfloat4 __attribute__((ext_vector_type(4)));

__device__ __forceinline__ float smooth_l1f(float d) {
    float ad = fabsf(d);
    return ad < 1.0f ? 0.5f * d * d : ad - 0.5f;
}

__device__ __forceinline__ void body(
    int i4, vfloat4 d4, vfloat4 l4, vfloat4 t4,
    const float* __restrict__ seg_r,
    float& cnt, float& s_loss, float& s_recon)
{
    int i  = i4 << 2;
    int w0 = i % W;                       // W%4==0: all 4 elems in same row
    const float* __restrict__ row = seg_r + (i - w0);
    #pragma unroll
    for (int k = 0; k < 4; ++k) {
        float lv = l4[k];
        float m = lv > 0.f ? 1.f : 0.f;
        cnt += m;
        float d = d4[k];
        s_loss += m * smooth_l1f(d - t4[k]);

        float sx  = (float)(w0 + k) - d;
        float x0f = floorf(sx);
        float wx  = sx - x0f;
        int x0 = (int)x0f;
        int x1 = x0 + 1;
        float m0 = (x0 >= 0 && x0 < W) ? 1.f : 0.f;
        float m1 = (x1 >= 0 && x1 < W) ? 1.f : 0.f;
        int x0c = min(max(x0, 0), W - 1);
        int x1c = min(max(x1, 0), W - 1);
        float g0 = row[x0c] * m0;          // cached gathers, hot L1/L2 window
        float g1 = row[x1c] * m1;
        float wv = fmaf(wx, g1 - g0, g0);
        float recon = 1.f / (1.f + __expf(-wv));
        s_recon += m * smooth_l1f(recon - lv);
    }
}

// Streaming, barrier-free, uniform-trip, 2x-interleaved fused loss.
__global__ __launch_bounds__(TPB) void loss_kernel(
    const float* __restrict__ dl,
    const float* __restrict__ seg_r,
    const float* __restrict__ dlgt,
    const float* __restrict__ lgt,
    double* __restrict__ ws)
{
    const int tid  = threadIdx.x;
    const int base = blockIdx.x * TPB + tid;
    float cnt = 0.f, s_loss = 0.f, s_recon = 0.f;

    #pragma unroll
    for (int p = 0; p < 4; p += 2) {
        int ia = base + p * STRIDE;
        int ib = base + (p + 1) * STRIDE;
        // issue BOTH points' stream loads before any compute
        vfloat4 da = __builtin_nontemporal_load((const vfloat4*)dl   + ia);
        vfloat4 la = __builtin_nontemporal_load((const vfloat4*)lgt  + ia);
        vfloat4 ta = __builtin_nontemporal_load((const vfloat4*)dlgt + ia);
        vfloat4 db = __builtin_nontemporal_load((const vfloat4*)dl   + ib);
        vfloat4 lb = __builtin_nontemporal_load((const vfloat4*)lgt  + ib);
        vfloat4 tb = __builtin_nontemporal_load((const vfloat4*)dlgt + ib);
        body(ia, da, la, ta, seg_r, cnt, s_loss, s_recon);
        body(ib, db, lb, tb, seg_r, cnt, s_loss, s_recon);
    }

    // block reduction: wave shuffle (double) then LDS across 4 waves
    double dc = (double)cnt, dlo = (double)s_loss, dre = (double)s_recon;
    for (int off = 32; off > 0; off >>= 1) {
        dc  += __shfl_down(dc,  off, 64);
        dlo += __shfl_down(dlo, off, 64);
        dre += __shfl_down(dre, off, 64);
    }
    __shared__ double sh[3][TPB / 64];
    int lane = tid & 63, wid = tid >> 6;
    if (lane == 0) { sh[0][wid] = dc; sh[1][wid] = dlo; sh[2][wid] = dre; }
    __syncthreads();

    if (tid == 0) {
        double c = 0, l = 0, r = 0;
        #pragma unroll
        for (int j = 0; j < TPB / 64; ++j) { c += sh[0][j]; l += sh[1][j]; r += sh[2][j]; }
        double* slot = ws + blockIdx.x * 4;   // plain stores, zero contention
        slot[0] = c; slot[1] = l; slot[2] = r;
    }
}

__global__ __launch_bounds__(256) void finalize_kernel(
    const double* __restrict__ ws, float* __restrict__ out)
{
    double c = 0, l = 0, r = 0;
    for (int i = threadIdx.x; i < NBLOCKS; i += 256) {
        const double* slot = ws + i * 4;
        c += slot[0]; l += slot[1]; r += slot[2];
    }
    for (int off = 32; off > 0; off >>= 1) {
        c += __shfl_down(c, off, 64);
        l += __shfl_down(l, off, 64);
        r += __shfl_down(r, off, 64);
    }
    __shared__ double sh[3][4];
    int lane = threadIdx.x & 63, wid = threadIdx.x >> 6;
    if (lane == 0) { sh[0][wid] = c; sh[1][wid] = l; sh[2][wid] = r; }
    __syncthreads();
    if (threadIdx.x == 0) {
        double cc = 0, ll = 0, rr = 0;
        #pragma unroll
        for (int j = 0; j < 4; ++j) { cc += sh[0][j]; ll += sh[1][j]; rr += sh[2][j]; }
        double loss = ll / cc;
        if (isnan(loss)) loss = 0.0;
        out[0] = (float)(loss + 0.5 * (rr / cc));
    }
}

extern "C" void kernel_launch(void* const* d_in, const int* in_sizes, int n_in,
                              void* d_out, int out_size, void* d_ws, size_t ws_size,
                              hipStream_t stream) {
    const float* dl    = (const float*)d_in[0];
    const float* seg_r = (const float*)d_in[1];
    const float* dlgt  = (const float*)d_in[2];
    const float* lgt   = (const float*)d_in[3];
    double* ws = (double*)d_ws;   // 4 * NBLOCKS doubles; every slot written each call

    loss_kernel<<<NBLOCKS, TPB, 0, stream>>>(dl, seg_r, dlgt, lgt, ws);
    finalize_kernel<<<1, 256, 0, stream>>>(ws, (float*)d_out);
}